// Round 1
// baseline (723.807 us; speedup 1.0000x reference)
//
#include <hip/hip_runtime.h>

#define HID 768
#define NB  128

using short8  = __attribute__((ext_vector_type(8))) short;
using short4_t = __attribute__((ext_vector_type(4))) short;
using float4_t = __attribute__((ext_vector_type(4))) float;

// RNE float -> bf16 bits (finite inputs only)
__device__ __forceinline__ short f2bf(float x) {
    union { float f; unsigned u; } c; c.f = x;
    unsigned r = c.u + 0x7fffu + ((c.u >> 16) & 1u);
    return (short)(r >> 16);
}
__device__ __forceinline__ float bf2f(short b) {
    union { unsigned u; float f; } c; c.u = ((unsigned)(unsigned short)b) << 16;
    return c.f;
}

// D[b,i] = sum_j op[i,j] * P[j,i],  P = X_b @ op^T  (reduce over k)
// One WG: (b, i-tile of 128). Loops 6 j-tiles x 24 k-steps of 32.
// A-operand = X rows (m=j), B-operand = op rows (n=i); K-dim = k contiguous in both.
__global__ __launch_bounds__(256, 3)
void diag_quad_kernel(const float* __restrict__ X, const float* __restrict__ OP,
                      float* __restrict__ out)
{
    constexpr int LDT = 40; // bf16 row stride (80B: 16B-aligned, 2-way-bank-free)
    __shared__ __align__(16) short Ah_s[128 * LDT];
    __shared__ __align__(16) short Al_s[128 * LDT];
    __shared__ __align__(16) short Bh_s[128 * LDT];
    __shared__ __align__(16) short Bl_s[128 * LDT];
    __shared__ float Dred[2][128];

    const int tid  = threadIdx.x;
    const int b    = blockIdx.x / 6;
    const int it   = blockIdx.x % 6;
    const int i0   = it * 128;
    const float* Xb = X + (size_t)b * HID * HID;

    const int lane = tid & 63;
    const int wave = tid >> 6;
    const int wj = wave & 1;        // j-half of WG tile
    const int wi = wave >> 1;       // i-half
    const int m16 = lane & 15;
    const int kg  = lane >> 4;      // 0..3

    // staging coords: 256 threads cover a 32x32 fp32 patch per pass, 4 passes
    const int srow = tid >> 3;          // 0..31
    const int scol = (tid & 7) * 4;     // 0,4,...,28

    float p[4] = {0.f, 0.f, 0.f, 0.f};  // per-lane D partials, one per tj (i sub-tile)

    for (int jt = 0; jt < 6; ++jt) {
        const int j0 = jt * 128;
        float4_t acc[4][4];
#pragma unroll
        for (int a = 0; a < 4; ++a)
#pragma unroll
            for (int c = 0; c < 4; ++c) acc[a][c] = (float4_t){0.f, 0.f, 0.f, 0.f};

        for (int ks = 0; ks < 24; ++ks) {
            const int k0 = ks * 32;
            __syncthreads();
            // stage: A = X[j0+row, k0..k0+31], B = OP[i0+row, k0..k0+31], split hi/lo bf16
#pragma unroll
            for (int pp = 0; pp < 4; ++pp) {
                const int row = pp * 32 + srow;
                const float4_t xv = *(const float4_t*)(Xb + (size_t)(j0 + row) * HID + k0 + scol);
                const float4_t ov = *(const float4_t*)(OP + (size_t)(i0 + row) * HID + k0 + scol);
                short4_t xh, xl, oh, ol;
#pragma unroll
                for (int e = 0; e < 4; ++e) {
                    const short hb = f2bf(xv[e]); xh[e] = hb; xl[e] = f2bf(xv[e] - bf2f(hb));
                    const short ob = f2bf(ov[e]); oh[e] = ob; ol[e] = f2bf(ov[e] - bf2f(ob));
                }
                *(short4_t*)(&Ah_s[row * LDT + scol]) = xh;
                *(short4_t*)(&Al_s[row * LDT + scol]) = xl;
                *(short4_t*)(&Bh_s[row * LDT + scol]) = oh;
                *(short4_t*)(&Bl_s[row * LDT + scol]) = ol;
            }
            __syncthreads();

            short8 fah[4], fal[4], fbh[4], fbl[4];
#pragma unroll
            for (int ti = 0; ti < 4; ++ti) {
                const int row = wj * 64 + ti * 16 + m16;
                fah[ti] = *(const short8*)(&Ah_s[row * LDT + kg * 8]);
                fal[ti] = *(const short8*)(&Al_s[row * LDT + kg * 8]);
            }
#pragma unroll
            for (int tj = 0; tj < 4; ++tj) {
                const int row = wi * 64 + tj * 16 + m16;
                fbh[tj] = *(const short8*)(&Bh_s[row * LDT + kg * 8]);
                fbl[tj] = *(const short8*)(&Bl_s[row * LDT + kg * 8]);
            }
#pragma unroll
            for (int ti = 0; ti < 4; ++ti)
#pragma unroll
                for (int tj = 0; tj < 4; ++tj) {
                    acc[ti][tj] = __builtin_amdgcn_mfma_f32_16x16x32_bf16(fah[ti], fbh[tj], acc[ti][tj], 0, 0, 0);
                    acc[ti][tj] = __builtin_amdgcn_mfma_f32_16x16x32_bf16(fal[ti], fbh[tj], acc[ti][tj], 0, 0, 0);
                    acc[ti][tj] = __builtin_amdgcn_mfma_f32_16x16x32_bf16(fah[ti], fbl[tj], acc[ti][tj], 0, 0, 0);
                }
        }

        // fold: C layout of 16x16x32 MFMA: n(=i) = lane&15, m(=j) = (lane>>4)*4 + reg
#pragma unroll
        for (int tj = 0; tj < 4; ++tj) {
            const int i_abs = i0 + wi * 64 + tj * 16 + m16;
            float s = 0.f;
#pragma unroll
            for (int ti = 0; ti < 4; ++ti) {
                const int j_base = j0 + wj * 64 + ti * 16 + kg * 4;
                const float4_t opv = *(const float4_t*)(OP + (size_t)i_abs * HID + j_base);
#pragma unroll
                for (int r = 0; r < 4; ++r) s += acc[ti][tj][r] * opv[r];
            }
            p[tj] += s;
        }
    }

    // reduce partials over the 4 kg groups (lane bits 4,5), then stage per-wave halves
#pragma unroll
    for (int tj = 0; tj < 4; ++tj) {
        p[tj] += __shfl_xor(p[tj], 16);
        p[tj] += __shfl_xor(p[tj], 32);
    }
    if (kg == 0) {
#pragma unroll
        for (int tj = 0; tj < 4; ++tj)
            Dred[wj][wi * 64 + tj * 16 + m16] = p[tj];
    }
    __syncthreads();
    if (tid < 128)
        out[(size_t)b * HID + i0 + tid] = Dred[0][tid] + Dred[1][tid];
}

// in-place row softmax: 128 rows x 768
__global__ __launch_bounds__(768)
void softmax_rows(float* __restrict__ out)
{
    const int row = blockIdx.x;
    const int t = threadIdx.x;
    const int wave = t >> 6, lane = t & 63;
    __shared__ float redm[12];
    __shared__ float reds[12];

    float v = out[(size_t)row * HID + t];

    float m = v;
#pragma unroll
    for (int o = 32; o >= 1; o >>= 1) m = fmaxf(m, __shfl_xor(m, o));
    if (lane == 0) redm[wave] = m;
    __syncthreads();
    if (t == 0) {
        float mm = redm[0];
        for (int w = 1; w < 12; ++w) mm = fmaxf(mm, redm[w]);
        redm[0] = mm;
    }
    __syncthreads();
    m = redm[0];

    const float e = expf(v - m);
    float s = e;
#pragma unroll
    for (int o = 32; o >= 1; o >>= 1) s += __shfl_xor(s, o);
    if (lane == 0) reds[wave] = s;
    __syncthreads();
    if (t == 0) {
        float ss = 0.f;
        for (int w = 0; w < 12; ++w) ss += reds[w];
        reds[0] = ss;
    }
    __syncthreads();
    out[(size_t)row * HID + t] = e / reds[0];
}

extern "C" void kernel_launch(void* const* d_in, const int* in_sizes, int n_in,
                              void* d_out, int out_size, void* d_ws, size_t ws_size,
                              hipStream_t stream)
{
    const float* X  = (const float*)d_in[0];   // [128,768,768] fp32
    const float* OP = (const float*)d_in[1];   // [768,768] fp32
    float* out = (float*)d_out;                // [128,768] fp32 (logits, then softmax in-place)

    hipLaunchKernelGGL(diag_quad_kernel, dim3(NB * 6), dim3(256), 0, stream, X, OP, out);
    hipLaunchKernelGGL(softmax_rows, dim3(NB), dim3(768), 0, stream, out);
}